// Round 1
// baseline (512.524 us; speedup 1.0000x reference)
//
#include <hip/hip_runtime.h>

#define BATCH 4096
#define SEQ   200
#define HID   64
#define G4    256   // 4*HID
#define BT    4     // batch rows per block

__device__ __forceinline__ float sigmoid_f(float x) {
    return 1.0f / (1.0f + __expf(-x));
}
__device__ __forceinline__ float tanh_f(float x) {
    // tanh(x) = 1 - 2/(exp(2x)+1); saturates correctly at +/-inf, no NaN
    float e = __expf(2.0f * x);
    return 1.0f - 2.0f / (e + 1.0f);
}

__global__ __launch_bounds__(256, 4)
void qlstm_fused(const float* __restrict__ x,      // [BATCH, SEQ] (inner dim 1 dropped)
                 const float* __restrict__ W_ih,   // [256]
                 const float* __restrict__ W_hh,   // [256, 64]
                 const float* __restrict__ b_ih,   // [256]
                 const float* __restrict__ b_hh,   // [256]
                 const float* __restrict__ W_lin,  // [SEQ*HID]
                 const float* __restrict__ b_lin,  // [1]
                 float* __restrict__ out)          // [BATCH]
{
    __shared__ float h_lds[BT][HID];          // current hidden state, fp32
    __shared__ float gates_lds[4][BT][HID];   // activated gates [q][b][j]
    __shared__ float x_lds[BT * SEQ];         // this block's inputs

    const int tid  = threadIdx.x;     // 0..255; also the W_hh row this thread owns
    const int wave = tid >> 6;        // gate index q in compute phase; batch b in pointwise
    const int lane = tid & 63;        // j
    const int b0   = blockIdx.x * BT;

    // ---- W_hh row `tid` into registers (64 VGPRs) ----
    float w[HID];
    {
        const float4* src = (const float4*)(W_hh + tid * HID);
        #pragma unroll
        for (int k = 0; k < HID / 4; ++k) {
            float4 v = src[k];
            w[4*k+0] = v.x; w[4*k+1] = v.y; w[4*k+2] = v.z; w[4*k+3] = v.w;
        }
    }
    const float wih  = W_ih[tid];
    const float bias = b_ih[tid] + b_hh[tid];

    // ---- stage this block's x (contiguous BT*SEQ floats) into LDS ----
    for (int i = tid; i < BT * SEQ; i += 256)
        x_lds[i] = x[b0 * SEQ + i];

    // init hidden state to zero
    ((float*)h_lds)[tid] = 0.0f;

    // per-thread state for pointwise cell (b = wave, j = lane)
    float c_state = 0.0f;
    float out_acc = 0.0f;

    __syncthreads();

    for (int t = 0; t < SEQ; ++t) {
        // ======== gate phase: gates[q*64+lane][b] for b = 0..3 ========
        float acc0 = fmaf(x_lds[0 * SEQ + t], wih, bias);
        float acc1 = fmaf(x_lds[1 * SEQ + t], wih, bias);
        float acc2 = fmaf(x_lds[2 * SEQ + t], wih, bias);
        float acc3 = fmaf(x_lds[3 * SEQ + t], wih, bias);

        #pragma unroll
        for (int hb = 0; hb < HID / 4; ++hb) {
            // broadcast reads: all lanes same address -> conflict-free
            float4 h0 = ((const float4*)h_lds[0])[hb];
            float4 h1 = ((const float4*)h_lds[1])[hb];
            float4 h2 = ((const float4*)h_lds[2])[hb];
            float4 h3 = ((const float4*)h_lds[3])[hb];
            acc0 = fmaf(h0.x, w[4*hb+0], acc0);
            acc0 = fmaf(h0.y, w[4*hb+1], acc0);
            acc0 = fmaf(h0.z, w[4*hb+2], acc0);
            acc0 = fmaf(h0.w, w[4*hb+3], acc0);
            acc1 = fmaf(h1.x, w[4*hb+0], acc1);
            acc1 = fmaf(h1.y, w[4*hb+1], acc1);
            acc1 = fmaf(h1.z, w[4*hb+2], acc1);
            acc1 = fmaf(h1.w, w[4*hb+3], acc1);
            acc2 = fmaf(h2.x, w[4*hb+0], acc2);
            acc2 = fmaf(h2.y, w[4*hb+1], acc2);
            acc2 = fmaf(h2.z, w[4*hb+2], acc2);
            acc2 = fmaf(h2.w, w[4*hb+3], acc2);
            acc3 = fmaf(h3.x, w[4*hb+0], acc3);
            acc3 = fmaf(h3.y, w[4*hb+1], acc3);
            acc3 = fmaf(h3.z, w[4*hb+2], acc3);
            acc3 = fmaf(h3.w, w[4*hb+3], acc3);
        }

        // activation: waves 0,1,3 = sigmoid (i,f,o); wave 2 = tanh (g)
        if (wave == 2) {
            acc0 = tanh_f(acc0); acc1 = tanh_f(acc1);
            acc2 = tanh_f(acc2); acc3 = tanh_f(acc3);
        } else {
            acc0 = sigmoid_f(acc0); acc1 = sigmoid_f(acc1);
            acc2 = sigmoid_f(acc2); acc3 = sigmoid_f(acc3);
        }
        gates_lds[wave][0][lane] = acc0;   // lane-consecutive -> conflict-free
        gates_lds[wave][1][lane] = acc1;
        gates_lds[wave][2][lane] = acc2;
        gates_lds[wave][3][lane] = acc3;

        __syncthreads();

        // ======== pointwise phase: cell (b = wave, j = lane) ========
        float ig = gates_lds[0][wave][lane];
        float fg = gates_lds[1][wave][lane];
        float gg = gates_lds[2][wave][lane];
        float og = gates_lds[3][wave][lane];

        c_state = fmaf(fg, c_state, ig * gg);
        float h_new = og * tanh_f(c_state);

        h_lds[wave][lane] = h_new;  // safe: all gate-phase reads completed pre-barrier
        out_acc = fmaf(h_new, W_lin[t * HID + lane], out_acc);

        __syncthreads();
    }

    // ---- reduce out_acc across the 64 lanes of this wave (b = b0 + wave) ----
    #pragma unroll
    for (int off = 32; off > 0; off >>= 1)
        out_acc += __shfl_down(out_acc, off, 64);
    if (lane == 0)
        out[b0 + wave] = out_acc + b_lin[0];
}

extern "C" void kernel_launch(void* const* d_in, const int* in_sizes, int n_in,
                              void* d_out, int out_size, void* d_ws, size_t ws_size,
                              hipStream_t stream) {
    const float* x     = (const float*)d_in[0];
    const float* W_ih  = (const float*)d_in[1];
    const float* W_hh  = (const float*)d_in[2];
    const float* b_ih  = (const float*)d_in[3];
    const float* b_hh  = (const float*)d_in[4];
    const float* W_lin = (const float*)d_in[5];
    const float* b_lin = (const float*)d_in[6];
    float* out = (float*)d_out;

    dim3 grid(BATCH / BT);   // 1024 blocks
    dim3 block(256);
    qlstm_fused<<<grid, block, 0, stream>>>(x, W_ih, W_hh, b_ih, b_hh,
                                            W_lin, b_lin, out);
}

// Round 2
// 199.831 us; speedup vs baseline: 2.5648x; 2.5648x over previous
//
#include <hip/hip_runtime.h>

#define SEQ 200
#define HID 64
#define BT  16
#define NBLK (4096 / BT)   // 256 blocks = 1 per CU

typedef _Float16 f16;
typedef _Float16 f16x8 __attribute__((ext_vector_type(8)));
typedef float    f32x4 __attribute__((ext_vector_type(4)));

__device__ __forceinline__ float sigmoid_f(float x) {
    return 1.0f / (1.0f + __expf(-x));
}
__device__ __forceinline__ float tanh_f(float x) {
    // tanh(x) = 1 - 2/(exp(2x)+1); saturates correctly, no NaN
    float e = __expf(2.0f * x);
    return 1.0f - 2.0f / (e + 1.0f);
}

// Per block: 16 batch rows, full 200-step LSTM + fused final linear.
// Gate GEMM per step: C[16 b x 256 gates] = h[16x64]_f16 @ W_hh^T_f16 (MFMA, fp32 acc).
// Wave w owns gate columns n in [16w,16w+16) of EACH quadrant i/f/g/o ->
// pointwise needs no LDS exchange: thread (l) holds i,f,g,o for cells
// (b = 4*(l>>4)+r, j = 16w + (l&15)), r=0..3.
__global__ __launch_bounds__(256, 1)
void qlstm_mfma(const float* __restrict__ x,      // [4096, 200]
                const float* __restrict__ W_ih,   // [256]
                const float* __restrict__ W_hh,   // [256, 64]
                const float* __restrict__ b_ih,   // [256]
                const float* __restrict__ b_hh,   // [256]
                const float* __restrict__ W_lin,  // [200*64]
                const float* __restrict__ b_lin,  // [1]
                float* __restrict__ out)          // [4096]
{
    __shared__ f16   x_lds[BT * 201];       // ~6.4 KB, pad 201 vs 200
    __shared__ float wl_lds[SEQ * HID];     // 51.2 KB
    __shared__ f16   h_frag[BT * HID];      // 2 KB, A-fragment order, XOR-swizzled 16B slots
    __shared__ float out_part[4][BT];

    const int tid = threadIdx.x;
    const int w   = tid >> 6;     // wave 0..3 -> j-block
    const int l   = tid & 63;
    const int m   = l & 15;       // A row / B col / C col
    const int a   = l >> 4;       // k-block (inputs) / C row-group
    const int b0  = blockIdx.x * BT;

    // ---- stage x as f16 ----
    for (int i = tid; i < BT * SEQ; i += 256) {
        int b = i / SEQ;
        int t = i - b * SEQ;
        x_lds[b * 201 + t] = (f16)x[(size_t)b0 * SEQ + i];
    }
    // ---- stage W_lin (f32, float4) ----
    {
        const float4* src = (const float4*)W_lin;
        float4* dst = (float4*)wl_lds;
        for (int i = tid; i < SEQ * HID / 4; i += 256) dst[i] = src[i];
    }
    // ---- zero h fragment buffer (h0 = 0) ----
    for (int i = tid; i < (BT * HID) / 2; i += 256) ((float*)h_frag)[i] = 0.0f;

    // ---- B fragments (W_hh^T) into registers, once ----
    // B[k][n] = W_hh[n][k]; lane l holds k = kk*32 + 8*(l>>4) + e (contiguous), n = base + (l&15).
    f16x8 Bf[4][2];
    float biasq[4], wihq[4];
    #pragma unroll
    for (int q = 0; q < 4; ++q) {
        const int n = q * 64 + w * 16 + m;
        biasq[q] = b_ih[n] + b_hh[n];
        wihq[q]  = W_ih[n];
        #pragma unroll
        for (int kk = 0; kk < 2; ++kk) {
            const float4* p = (const float4*)(W_hh + n * HID + kk * 32 + a * 8);
            float4 lo = p[0], hi = p[1];
            f16x8 f;
            f[0] = (f16)lo.x; f[1] = (f16)lo.y; f[2] = (f16)lo.z; f[3] = (f16)lo.w;
            f[4] = (f16)hi.x; f[5] = (f16)hi.y; f[6] = (f16)hi.z; f[7] = (f16)hi.w;
            Bf[q][kk] = f;
        }
    }

    const int jj = w * 16 + m;   // this thread's hidden index j
    // A-frag read addrs: row m, slot s = kk*4 + a, swizzled: byte = m*128 + ((s ^ (m&7))<<4)
    const int ra0 = m * 128 + (((0 + a) ^ (m & 7)) << 4);
    const int ra1 = m * 128 + (((4 + a) ^ (m & 7)) << 4);
    // h write addrs: cell (br, jj): byte = br*128 + (((jj>>3) ^ (br&7))<<4) + (jj&7)*2
    int wa[4];
    #pragma unroll
    for (int r = 0; r < 4; ++r) {
        const int br = 4 * a + r;
        wa[r] = br * 128 + ((((jj >> 3)) ^ (br & 7)) << 4) + (jj & 7) * 2;
    }

    float c_state[4] = {0.f, 0.f, 0.f, 0.f};
    float out_acc[4] = {0.f, 0.f, 0.f, 0.f};

    __syncthreads();

    for (int t = 0; t < SEQ; ++t) {
        // ---- gate phase ----
        const f16x8 A0 = *(const f16x8*)((const char*)h_frag + ra0);
        const f16x8 A1 = *(const f16x8*)((const char*)h_frag + ra1);
        float xr[4];
        #pragma unroll
        for (int r = 0; r < 4; ++r) xr[r] = (float)x_lds[(4 * a + r) * 201 + t];
        const float wlin = wl_lds[t * HID + jj];

        f32x4 acc[4];
        #pragma unroll
        for (int q = 0; q < 4; ++q) {
            f32x4 ini;
            #pragma unroll
            for (int r = 0; r < 4; ++r) ini[r] = fmaf(xr[r], wihq[q], biasq[q]);
            ini    = __builtin_amdgcn_mfma_f32_16x16x32_f16(A0, Bf[q][0], ini, 0, 0, 0);
            acc[q] = __builtin_amdgcn_mfma_f32_16x16x32_f16(A1, Bf[q][1], ini, 0, 0, 0);
        }

        __syncthreads();   // everyone done reading h_frag before overwrite

        // ---- pointwise phase: 4 cells in registers ----
        #pragma unroll
        for (int r = 0; r < 4; ++r) {
            const float ig = sigmoid_f(acc[0][r]);
            const float fg = sigmoid_f(acc[1][r]);
            const float gg = tanh_f(acc[2][r]);
            const float og = sigmoid_f(acc[3][r]);
            c_state[r] = fmaf(fg, c_state[r], ig * gg);
            const float h = og * tanh_f(c_state[r]);
            out_acc[r] = fmaf(h, wlin, out_acc[r]);
            *(f16*)((char*)h_frag + wa[r]) = (f16)h;
        }

        __syncthreads();   // h_frag writes visible before next read
    }

    // ---- reduce out_acc over j: 16 lanes within group, then 4 waves via LDS ----
    #pragma unroll
    for (int r = 0; r < 4; ++r) {
        float v = out_acc[r];
        v += __shfl_xor(v, 1, 64);
        v += __shfl_xor(v, 2, 64);
        v += __shfl_xor(v, 4, 64);
        v += __shfl_xor(v, 8, 64);
        if (m == 0) out_part[w][4 * a + r] = v;
    }
    __syncthreads();
    if (tid < BT) {
        float s = out_part[0][tid] + out_part[1][tid]
                + out_part[2][tid] + out_part[3][tid];
        out[b0 + tid] = s + b_lin[0];
    }
}

extern "C" void kernel_launch(void* const* d_in, const int* in_sizes, int n_in,
                              void* d_out, int out_size, void* d_ws, size_t ws_size,
                              hipStream_t stream) {
    const float* x     = (const float*)d_in[0];
    const float* W_ih  = (const float*)d_in[1];
    const float* W_hh  = (const float*)d_in[2];
    const float* b_ih  = (const float*)d_in[3];
    const float* b_hh  = (const float*)d_in[4];
    const float* W_lin = (const float*)d_in[5];
    const float* b_lin = (const float*)d_in[6];
    float* out = (float*)d_out;

    dim3 grid(NBLK);
    dim3 block(256);
    qlstm_mfma<<<grid, block, 0, stream>>>(x, W_ih, W_hh, b_ih, b_hh,
                                           W_lin, b_lin, out);
}